// Round 5
// baseline (367.366 us; speedup 1.0000x reference)
//
#include <hip/hip_runtime.h>

#define EPS 1e-8f

using f32x4 = __attribute__((ext_vector_type(4))) float;

// Direct global->LDS DMA, 16B per lane: lane l's 16B lands at lds_base + l*16.
// Zero landing VGPRs -- breaks the VGPR bytes-in-flight cap (R1/R3: 52 VGPR ->
// 4 waves/SIMD -> ~2.6 TB/s ceiling for VGPR-landed streams).
// Sync discipline: R4's hand-counted inline-asm vmcnt pipeline FAILED
// correctness (absmax 1.9e4). This version uses the verified m97 structure:
// __syncthreads() as the drain (compiler emits s_waitcnt vmcnt(0) before
// s_barrier). Stage-next / consume-current / barrier; DMAs in flight always
// target the buffer NOT being read.
#define GLD16(g, l) __builtin_amdgcn_global_load_lds( \
    (const __attribute__((address_space(1))) void*)(g), \
    (__attribute__((address_space(3))) void*)(l), 16, 0, 0)

// B=4, C=128, H=W=256, HW=65536, mask 128x128 per batch (nearest-upsample 2x2)
// Phase 1: partial moment sums. grid = 512*4, 256 threads, 8 steps of 2048 els.
// LDS 32KB = 2 x (x1:2048 | x2:2048) floats; wave w owns [w*512,+512) of each.
// stats[(bc*4+chunk)*12 + j]:
//  j: 0 Σx1 m   1 Σx1 m³   2 Σx1² m⁴   3..5 same for x2
//     6 Σx1 om  7 Σx1 om³  8 Σx1² om⁴  9..11 same for x2
__global__ __launch_bounds__(256) void k_stats(
    const float* __restrict__ x1,
    const float* __restrict__ x2,
    const float* __restrict__ mask,
    float* __restrict__ stats)
{
    __shared__ float lds[2][4096];   // 32KB -> 5 blocks/CU

    int blk   = blockIdx.x;        // [0, 2048)
    int chunk = blk & 3;
    int bc    = blk >> 2;          // b*128 + c
    int b     = bc >> 7;
    int tid   = threadIdx.x;
    int wv    = tid >> 6, ln = tid & 63;

    // wave slice: step s covers plane els [chunk*16384 + s*2048 + wv*512, +512)
    const size_t pbase = (size_t)bc * 65536 + (size_t)chunk * 16384
                       + (size_t)(wv * 512 + ln * 8);
    const float* sx1 = x1 + pbase;
    const float* sx2 = x2 + pbase;
    // mask row for the wave's 2 plane rows (both rows map to one mask row)
    const float* mbase = mask + b * 16384 + (chunk * 32 + wv) * 128 + (ln & 31) * 4;

    float a[12];
#pragma unroll
    for (int j = 0; j < 12; ++j) a[j] = 0.f;

    // stage step S into buffer D: lane ln's floats [ln*8,+4) -> lds float ln*4
#define KS_STAGE(D, S) { \
      float* Lx1 = &lds[D][wv * 512]; \
      float* Lx2 = &lds[D][2048 + wv * 512]; \
      const float* g1 = sx1 + (S) * 2048; \
      const float* g2 = sx2 + (S) * 2048; \
      GLD16(g1, Lx1); GLD16(g1 + 4, Lx1 + 256); \
      GLD16(g2, Lx2); GLD16(g2 + 4, Lx2 + 256); }

    KS_STAGE(0, 0)
    __syncthreads();               // drain: buf0 ready

    for (int s = 0; s < 8; ++s) {
        int cur = s & 1;
        if (s < 7) KS_STAGE(cur ^ 1, s + 1)        // DMA targets other buffer
        f32x4 mv = *(const f32x4*)(mbase + s * 512);
        const float* LC1 = &lds[cur][wv * 512];
        const float* LC2 = &lds[cur][2048 + wv * 512];
        f32x4 v1a = *(const f32x4*)(LC1 + ln * 4);
        f32x4 v1b = *(const f32x4*)(LC1 + 256 + ln * 4);
        f32x4 v2a = *(const f32x4*)(LC2 + ln * 4);
        f32x4 v2b = *(const f32x4*)(LC2 + 256 + ln * 4);
#pragma unroll
        for (int j = 0; j < 8; ++j) {
            float m  = mv[j >> 1];
            float om = 1.f - m;
            float m2 = m * m, om2 = om * om;
            float f1 = (j < 4) ? v1a[j & 3] : v1b[j & 3];
            float f2 = (j < 4) ? v2a[j & 3] : v2b[j & 3];
            float p1 = f1 * m2,  p2 = f2 * m2;
            a[0] += f1 * m;  a[1] += p1 * m;  a[2] += p1 * p1;
            a[3] += f2 * m;  a[4] += p2 * m;  a[5] += p2 * p2;
            float q1 = f1 * om2, q2 = f2 * om2;
            a[6] += f1 * om; a[7]  += q1 * om; a[8]  += q1 * q1;
            a[9] += f2 * om; a[10] += q2 * om; a[11] += q2 * q2;
        }
        __syncthreads();           // drain stage(s+1); also frees buf for reuse
    }
#undef KS_STAGE

#pragma unroll
    for (int j = 0; j < 12; ++j)
#pragma unroll
        for (int d = 32; d > 0; d >>= 1)
            a[j] += __shfl_down(a[j], d, 64);

    // reduction scratch reuses buf0 (last read at s=6; no DMAs in flight --
    // final loop barrier drained everything). Keeps LDS at exactly 32KB.
    if (ln == 0) {
#pragma unroll
        for (int j = 0; j < 12; ++j) lds[0][wv * 12 + j] = a[j];
    }
    __syncthreads();
    if (tid < 12) {
        float v = lds[0][tid] + lds[0][12 + tid] + lds[0][24 + tid] + lds[0][36 + tid];
        stats[(size_t)blk * 12 + tid] = v;
    }
}

// Phase 2: per-batch stats + 4 small matvecs. grid = B*4, 256 threads. (as R3)
__global__ __launch_bounds__(256) void k_mod(
    const float* __restrict__ mask,
    const float* __restrict__ w_in_mean,
    const float* __restrict__ w_in_var,
    const float* __restrict__ w_out_mean,
    const float* __restrict__ w_out_var,
    const float* __restrict__ stats,
    float* __restrict__ derived)
{
    int b   = blockIdx.x >> 2;
    int mat = blockIdx.x & 3;
    int tid = threadIdx.x;

    const float* mp = mask + b * 16384;
    float sm = 0.f, sm2 = 0.f;
    for (int it = 0; it < 16; ++it) {
        const f32x4 mv = *(const f32x4*)(mp + (it * 256 + tid) * 4);
#pragma unroll
        for (int j = 0; j < 4; ++j) { float m = mv[j]; sm += m; sm2 += m * m; }
    }
#pragma unroll
    for (int d = 32; d > 0; d >>= 1) {
        sm  += __shfl_down(sm, d, 64);
        sm2 += __shfl_down(sm2, d, 64);
    }
    __shared__ float rr[8];
    __shared__ float SMs, SM2s;
    int wv = tid >> 6, ln = tid & 63;
    if (ln == 0) { rr[wv] = sm; rr[4 + wv] = sm2; }
    __syncthreads();
    if (tid == 0) {
        SMs  = 4.f * (rr[0] + rr[1] + rr[2] + rr[3]);
        SM2s = 4.f * (rr[4] + rr[5] + rr[6] + rr[7]);
    }
    __syncthreads();
    float SM = SMs, SM2 = SM2s;
    float n_in  = SM + EPS;
    float n_out = 65536.f - SM + EPS;
    float SOM2  = 65536.f - 2.f * SM + SM2;

    __shared__ float vec[256];

    if (tid < 128) {
        int c = tid;
        const float* st = stats + (size_t)(b * 128 + c) * 4 * 12;
        float s[12];
#pragma unroll
        for (int j = 0; j < 12; ++j)
            s[j] = (st[j] + st[12 + j]) + (st[24 + j] + st[36 + j]);
        float mi1 = s[0] / n_in;
        float vi1 = fmaxf((s[2] - 2.f * mi1 * s[1] + mi1 * mi1 * SM2) / n_in, 0.f);
        float mi2 = s[3] / n_in;
        float vi2 = fmaxf((s[5] - 2.f * mi2 * s[4] + mi2 * mi2 * SM2) / n_in, 0.f);
        float mo1 = s[6] / n_out;
        float vo1 = fmaxf((s[8] - 2.f * mo1 * s[7] + mo1 * mo1 * SOM2) / n_out, 0.f);
        float mo2 = s[9] / n_out;
        float vo2 = fmaxf((s[11] - 2.f * mo2 * s[10] + mo2 * mo2 * SOM2) / n_out, 0.f);
        float v0, v1;
        if (mat == 0)      { v0 = mi1; v1 = mi2; }
        else if (mat == 1) { v0 = vi1; v1 = vi2; }
        else if (mat == 2) { v0 = mo1; v1 = mo2; }
        else               { v0 = vo1; v1 = vo2; }
        vec[c] = v0; vec[128 + c] = v1;
        if (mat == 0) {
            float* d = derived + (size_t)(b * 128 + c) * 8;
            d[0] = mi1; d[1] = rsqrtf(vi1 + EPS);
            d[2] = mo1; d[3] = rsqrtf(vo1 + EPS);
        }
    }
    __syncthreads();

    const float* wp = (mat == 0) ? w_in_mean :
                      (mat == 1) ? w_in_var :
                      (mat == 2) ? w_out_mean : w_out_var;
    int row = tid >> 1, half = tid & 1;
    const float* wr = wp + row * 256 + half * 128;
    const float* vp = vec + half * 128;
    float acc = 0.f;
    for (int k = 0; k < 128; k += 4) {
        f32x4 w4 = *(const f32x4*)(wr + k);
#pragma unroll
        for (int j = 0; j < 4; ++j) acc += w4[j] * vp[k + j];
    }
    acc += __shfl_xor(acc, 1, 64);
    if (half == 0)
        derived[(size_t)(b * 128 + row) * 8 + 4 + mat] = acc;
}

// Phase 3: elementwise apply, DMA-staged like k_stats (x1 only).
// LDS 16KB -> 8 blocks/CU (wave-capped), 32 waves/CU.
__global__ __launch_bounds__(256) void k_apply(
    const float* __restrict__ x1,
    const float* __restrict__ mask,
    const float* __restrict__ derived,
    float* __restrict__ out)
{
    __shared__ float lds[2][2048];    // 16KB

    int blk   = blockIdx.x;        // [0, 2048)
    int bc    = blk >> 2;
    int chunk = blk & 3;
    int b     = bc >> 7;
    int tid   = threadIdx.x;
    int wv    = tid >> 6, ln = tid & 63;

    f32x4 d0 = *(const f32x4*)(derived + (size_t)bc * 8);
    f32x4 d1 = *(const f32x4*)(derived + (size_t)bc * 8 + 4);
    float ci1 = d0[1] * d1[1];          // inv_in * av_in
    float ci0 = d1[0] - d0[0] * ci1;    // am_in - mean_in*ci1
    float co1 = d0[3] * d1[3];
    float co0 = d1[2] - d0[2] * co1;

    const size_t pbase = (size_t)bc * 65536 + (size_t)chunk * 16384
                       + (size_t)(wv * 512 + ln * 8);
    const float* sx = x1 + pbase;
    float* op = out + pbase;
    const float* mbase = mask + b * 16384 + (chunk * 32 + wv) * 128 + (ln & 31) * 4;

#define KA_STAGE(D, S) { \
      float* L = &lds[D][wv * 512]; \
      const float* g = sx + (S) * 2048; \
      GLD16(g, L); GLD16(g + 4, L + 256); }

    KA_STAGE(0, 0)
    __syncthreads();

    for (int s = 0; s < 8; ++s) {
        int cur = s & 1;
        if (s < 7) KA_STAGE(cur ^ 1, s + 1)
        f32x4 mv = *(const f32x4*)(mbase + s * 512);
        const float* LC = &lds[cur][wv * 512];
        f32x4 xa = *(const f32x4*)(LC + ln * 4);
        f32x4 xb = *(const f32x4*)(LC + 256 + ln * 4);
        f32x4 oa, ob;
#pragma unroll
        for (int j = 0; j < 8; ++j) {
            float m  = mv[j >> 1];
            float om = 1.f - m;
            float x  = (j < 4) ? xa[j & 3] : xb[j & 3];
            float r  = x * (m * m * ci1 + om * om * co1) + ci0 * m + co0 * om;
            if (j < 4) oa[j & 3] = r; else ob[j & 3] = r;
        }
        __builtin_nontemporal_store(oa, (f32x4*)(op + s * 2048));
        __builtin_nontemporal_store(ob, (f32x4*)(op + s * 2048 + 4));
        __syncthreads();
    }
#undef KA_STAGE
}

extern "C" void kernel_launch(void* const* d_in, const int* in_sizes, int n_in,
                              void* d_out, int out_size, void* d_ws, size_t ws_size,
                              hipStream_t stream) {
    const float* x1        = (const float*)d_in[0];
    const float* x2        = (const float*)d_in[1];
    const float* mask      = (const float*)d_in[2];
    const float* w_in_mean = (const float*)d_in[3];
    const float* w_in_var  = (const float*)d_in[4];
    const float* w_out_mean= (const float*)d_in[5];
    const float* w_out_var = (const float*)d_in[6];

    float* stats   = (float*)d_ws;              // 2048 * 12 floats
    float* derived = stats + 2048 * 12;         // 512 * 8 floats
    float* out = (float*)d_out;

    k_stats<<<512 * 4, 256, 0, stream>>>(x1, x2, mask, stats);
    k_mod<<<4 * 4, 256, 0, stream>>>(mask, w_in_mean, w_in_var, w_out_mean, w_out_var,
                                     stats, derived);
    k_apply<<<512 * 4, 256, 0, stream>>>(x1, mask, derived, out);
}